// Round 9
// baseline (23.270 us; speedup 1.0000x reference)
//
#include <hip/hip_runtime.h>
#include <math.h>

// Problem constants (fixed by setup_inputs)
#define B 4
#define H 64
#define W 64
#define C 256
#define R 128
#define PH 7
#define PW 7

#define CELLS_TOTAL (B * R * PH * PW)   // 25088
#define BLOCKS_TOTAL (CELLS_TOTAL / 4)  // 6272
#define BLOCKS_PER_HALF 784             // 6272 / 8

typedef float f32x4 __attribute__((ext_vector_type(4)));

__global__ __launch_bounds__(256) void roi_pool_kernel(
    const float* __restrict__ fm,      // [B,H,W,C]
    const float* __restrict__ rois,    // [B,R,4] = x1,y1,x2,y2
    float* __restrict__ out)           // [B,R,PH,PW,C]
{
    const int wave = threadIdx.x >> 6;
    const int lane = threadIdx.x & 63;

    // XCD-aware swizzle: blockIdx % 8 = XCD (round-robin dispatch).
    // Pin each XCD to one batch b (2 XCDs per batch) so the 4.0 MiB per-batch
    // fm slice stays resident in that XCD's 4 MiB L2.
    const int xcd  = blockIdx.x & 7;        // 0..7
    const int slot = blockIdx.x >> 3;       // 0..783
    const int b    = xcd >> 1;              // 0..3
    const int half = xcd & 1;               // 0..1
    const int cell_in_b = (half * BLOCKS_PER_HALF + slot) * 4 + wave;  // 0..6271

    // decode (r, p, q) from cell_in_b, row-major [R,PH,PW]
    const int q = cell_in_b % PW;
    int t = cell_in_b / PW;
    const int p = t % PH;
    const int r = t / PH;

    // Scalarize the ROI fetch: index is wave-uniform -> s_load path.
    const int ridx = __builtin_amdgcn_readfirstlane(b * R + r);
    const float* roi = rois + (size_t)ridx * 4;
    const float x1 = roi[0], y1 = roi[1], x2 = roi[2], y2 = roi[3];

    // jnp.round = round-half-to-even -> rintf under default RN mode
    int ws = max((int)rintf(x1), 0);
    int hs = max((int)rintf(y1), 0);
    int we = min((int)rintf(x2), W);
    int he = min((int)rintf(y2), H);

    // TF reshape quirk: out[b,r,p,q,:] = max over h-bin q, w-bin p.
    // Replicate exact fp32 arithmetic of the reference.
    const float hstep = (float)(he - hs) / 7.0f;
    const float wstep = (float)(we - ws) / 7.0f;
    const int hlo = hs + (int)((float)q * hstep);
    const int hhi = (q < PH - 1) ? (hs + (int)((float)(q + 1) * hstep)) : he;
    const int wlo = ws + (int)((float)p * wstep);
    const int whi = (p < PW - 1) ? (ws + (int)((float)(p + 1) * wstep)) : we;

    const int nw = whi - wlo;              // >= 1 (no empty bins by construction)
    const int nh = hhi - hlo;
    const int n  = nh * nw;                // total (h,w) visits, wave-uniform

    const float* gp = fm + ((size_t)(b * H + hlo) * W + wlo) * C + lane * 4;
    int gw = 0;
    const size_t rstep = (size_t)(W - nw + 1) * C;  // last elem of row -> first of next row

    f32x4 acc = { -INFINITY, -INFINITY, -INFINITY, -INFINITY };

// Non-temporal load: structural L1 hit rate is ~0 (reuse spread over 64 CUs),
// so skip L1 allocation on the fm stream.
#define LOADV(dst) (dst) = __builtin_nontemporal_load((const f32x4*)gp)
#define ADV() { if (++gw == nw) { gw = 0; gp += rstep; } else { gp += (size_t)C; } }
#define FM(vv) { acc.x = fmaxf(acc.x, (vv).x); acc.y = fmaxf(acc.y, (vv).y); \
                 acc.z = fmaxf(acc.z, (vv).z); acc.w = fmaxf(acc.w, (vv).w); }

    if (n >= 8) {
        // 8-deep rotating software pipeline, exactly n loads.
        f32x4 v0, v1, v2, v3, v4, v5, v6, v7;
        LOADV(v0); ADV(); LOADV(v1); ADV(); LOADV(v2); ADV(); LOADV(v3); ADV();
        LOADV(v4); ADV(); LOADV(v5); ADV(); LOADV(v6); ADV(); LOADV(v7); ADV();
        int k = n - 8;
        while (k >= 8) {
            FM(v0); LOADV(v0); ADV();
            FM(v1); LOADV(v1); ADV();
            FM(v2); LOADV(v2); ADV();
            FM(v3); LOADV(v3); ADV();
            FM(v4); LOADV(v4); ADV();
            FM(v5); LOADV(v5); ADV();
            FM(v6); LOADV(v6); ADV();
            FM(v7); LOADV(v7); ADV();
            k -= 8;
        }
        // tail: k in [0,7]; fmax is commutative, every slot drains at the end.
        if (k > 0) { FM(v0); LOADV(v0); ADV(); }
        if (k > 1) { FM(v1); LOADV(v1); ADV(); }
        if (k > 2) { FM(v2); LOADV(v2); ADV(); }
        if (k > 3) { FM(v3); LOADV(v3); ADV(); }
        if (k > 4) { FM(v4); LOADV(v4); ADV(); }
        if (k > 5) { FM(v5); LOADV(v5); ADV(); }
        if (k > 6) { FM(v6); LOADV(v6); ADV(); }
        FM(v0); FM(v1); FM(v2); FM(v3); FM(v4); FM(v5); FM(v6); FM(v7);
    } else if (n >= 4) {
        f32x4 v0, v1, v2, v3;
        LOADV(v0); ADV(); LOADV(v1); ADV(); LOADV(v2); ADV(); LOADV(v3); ADV();
        int k = n - 4;
        if (k > 0) { FM(v0); LOADV(v0); ADV(); }
        if (k > 1) { FM(v1); LOADV(v1); ADV(); }
        if (k > 2) { FM(v2); LOADV(v2); ADV(); }
        FM(v0); FM(v1); FM(v2); FM(v3);
    } else {
        for (int i = 0; i < n; ++i) {
            f32x4 v; LOADV(v); ADV(); FM(v);
        }
    }

    // Non-temporal store: out (25.7 MB) is write-once; keep it from evicting
    // the fm slice out of the per-XCD L2.
    const int cell = ((b * R + r) * PH + p) * PW + q;
    float* op = out + (size_t)cell * C + lane * 4;
    __builtin_nontemporal_store(acc, (f32x4*)op);
}

extern "C" void kernel_launch(void* const* d_in, const int* in_sizes, int n_in,
                              void* d_out, int out_size, void* d_ws, size_t ws_size,
                              hipStream_t stream) {
    const float* fm   = (const float*)d_in[0];
    const float* rois = (const float*)d_in[1];
    float* out = (float*)d_out;

    roi_pool_kernel<<<BLOCKS_TOTAL, 256, 0, stream>>>(fm, rois, out);
}

// Round 10
// 16.191 us; speedup vs baseline: 1.4373x; 1.4373x over previous
//
#include <hip/hip_runtime.h>
#include <math.h>

// Problem constants (fixed by setup_inputs)
#define B 4
#define H 64
#define W 64
#define C 256
#define R 128
#define PH 7
#define PW 7

#define CELLS_TOTAL (B * R * PH * PW)   // 25088
#define WAVES_PER_BLOCK 8               // 512-thread blocks
#define BLOCKS_TOTAL (CELLS_TOTAL / WAVES_PER_BLOCK)  // 3136
#define SLOTS_PER_CLASS (BLOCKS_TOTAL / 8)            // 392

typedef float f32x4 __attribute__((ext_vector_type(4)));

__global__ __launch_bounds__(512) void roi_pool_kernel(
    const float* __restrict__ fm,      // [B,H,W,C]
    const float* __restrict__ rois,    // [B,R,4] = x1,y1,x2,y2
    float* __restrict__ out)           // [B,R,PH,PW,C]
{
    const int wave = threadIdx.x >> 6;      // 0..7
    const int lane = threadIdx.x & 63;

    // XCD-aware swizzle: blockIdx % 8 = XCD (round-robin dispatch).
    // Pin each XCD to one batch b (2 XCDs per batch) so the 4.0 MiB per-batch
    // fm slice stays resident in that XCD's 4 MiB L2.
    const int xcd  = blockIdx.x & 7;        // 0..7
    const int slot = blockIdx.x >> 3;       // 0..391
    const int b    = xcd >> 1;              // 0..3
    const int half = xcd & 1;               // 0..1
    const int cell_in_b = (half * SLOTS_PER_CLASS + slot) * WAVES_PER_BLOCK + wave; // 0..6271

    // decode (r, p, q) from cell_in_b, row-major [R,PH,PW]
    const int q = cell_in_b % PW;
    int t = cell_in_b / PW;
    const int p = t % PH;
    const int r = t / PH;

    // Scalarize the ROI fetch: index is wave-uniform -> s_load path.
    const int ridx = __builtin_amdgcn_readfirstlane(b * R + r);
    const float* roi = rois + (size_t)ridx * 4;
    const float x1 = roi[0], y1 = roi[1], x2 = roi[2], y2 = roi[3];

    // jnp.round = round-half-to-even -> rintf under default RN mode
    int ws = max((int)rintf(x1), 0);
    int hs = max((int)rintf(y1), 0);
    int we = min((int)rintf(x2), W);
    int he = min((int)rintf(y2), H);

    // TF reshape quirk: out[b,r,p,q,:] = max over h-bin q, w-bin p.
    // Replicate exact fp32 arithmetic of the reference.
    const float hstep = (float)(he - hs) / 7.0f;
    const float wstep = (float)(we - ws) / 7.0f;
    const int hlo = hs + (int)((float)q * hstep);
    const int hhi = (q < PH - 1) ? (hs + (int)((float)(q + 1) * hstep)) : he;
    const int wlo = ws + (int)((float)p * wstep);
    const int whi = (p < PW - 1) ? (ws + (int)((float)(p + 1) * wstep)) : we;

    const int nw = whi - wlo;              // >= 1 (no empty bins by construction)
    const int nh = hhi - hlo;
    const int n  = nh * nw;                // total (h,w) visits, wave-uniform

    const float* gp = fm + ((size_t)(b * H + hlo) * W + wlo) * C + lane * 4;
    int gw = 0;
    const size_t rstep = (size_t)(W - nw + 1) * C;  // last elem of row -> first of next row

    f32x4 acc = { -INFINITY, -INFINITY, -INFINITY, -INFINITY };

#define LOADV(dst) (dst) = *(const f32x4*)gp
#define ADV() { if (++gw == nw) { gw = 0; gp += rstep; } else { gp += (size_t)C; } }
#define FM(vv) { acc.x = fmaxf(acc.x, (vv).x); acc.y = fmaxf(acc.y, (vv).y); \
                 acc.z = fmaxf(acc.z, (vv).z); acc.w = fmaxf(acc.w, (vv).w); }

    if (n >= 8) {
        // 8-deep rotating software pipeline, exactly n loads.
        f32x4 v0, v1, v2, v3, v4, v5, v6, v7;
        LOADV(v0); ADV(); LOADV(v1); ADV(); LOADV(v2); ADV(); LOADV(v3); ADV();
        LOADV(v4); ADV(); LOADV(v5); ADV(); LOADV(v6); ADV(); LOADV(v7); ADV();
        int k = n - 8;
        while (k >= 8) {
            FM(v0); LOADV(v0); ADV();
            FM(v1); LOADV(v1); ADV();
            FM(v2); LOADV(v2); ADV();
            FM(v3); LOADV(v3); ADV();
            FM(v4); LOADV(v4); ADV();
            FM(v5); LOADV(v5); ADV();
            FM(v6); LOADV(v6); ADV();
            FM(v7); LOADV(v7); ADV();
            k -= 8;
        }
        // tail: k in [0,7]; fmax is commutative, every slot drains at the end.
        if (k > 0) { FM(v0); LOADV(v0); ADV(); }
        if (k > 1) { FM(v1); LOADV(v1); ADV(); }
        if (k > 2) { FM(v2); LOADV(v2); ADV(); }
        if (k > 3) { FM(v3); LOADV(v3); ADV(); }
        if (k > 4) { FM(v4); LOADV(v4); ADV(); }
        if (k > 5) { FM(v5); LOADV(v5); ADV(); }
        if (k > 6) { FM(v6); LOADV(v6); ADV(); }
        FM(v0); FM(v1); FM(v2); FM(v3); FM(v4); FM(v5); FM(v6); FM(v7);
    } else if (n >= 4) {
        f32x4 v0, v1, v2, v3;
        LOADV(v0); ADV(); LOADV(v1); ADV(); LOADV(v2); ADV(); LOADV(v3); ADV();
        int k = n - 4;
        if (k > 0) { FM(v0); LOADV(v0); ADV(); }
        if (k > 1) { FM(v1); LOADV(v1); ADV(); }
        if (k > 2) { FM(v2); LOADV(v2); ADV(); }
        FM(v0); FM(v1); FM(v2); FM(v3);
    } else {
        for (int i = 0; i < n; ++i) {
            f32x4 v; LOADV(v); ADV(); FM(v);
        }
    }

    // Non-temporal store: out (25.7 MB) is write-once; keep it from evicting
    // the fm slice out of the per-XCD L2.
    const int cell = ((b * R + r) * PH + p) * PW + q;
    float* op = out + (size_t)cell * C + lane * 4;
    __builtin_nontemporal_store(acc, (f32x4*)op);
}

extern "C" void kernel_launch(void* const* d_in, const int* in_sizes, int n_in,
                              void* d_out, int out_size, void* d_ws, size_t ws_size,
                              hipStream_t stream) {
    const float* fm   = (const float*)d_in[0];
    const float* rois = (const float*)d_in[1];
    float* out = (float*)d_out;

    roi_pool_kernel<<<BLOCKS_TOTAL, 512, 0, stream>>>(fm, rois, out);
}

// Round 11
// 15.315 us; speedup vs baseline: 1.5194x; 1.0572x over previous
//
#include <hip/hip_runtime.h>
#include <math.h>

// Problem constants (fixed by setup_inputs)
#define B 4
#define H 64
#define W 64
#define C 256
#define R 128
#define PH 7
#define PW 7

#define CELLS_TOTAL (B * R * PH * PW)   // 25088
#define BLOCKS_TOTAL (CELLS_TOTAL / 4)  // 6272
#define BLOCKS_PER_HALF 784             // 6272 / 8

typedef float f32x4 __attribute__((ext_vector_type(4)));

__global__ __launch_bounds__(256) void roi_pool_kernel(
    const float* __restrict__ fm,      // [B,H,W,C]
    const float* __restrict__ rois,    // [B,R,4] = x1,y1,x2,y2
    float* __restrict__ out)           // [B,R,PH,PW,C]
{
    const int wave = threadIdx.x >> 6;
    const int lane = threadIdx.x & 63;

    // XCD-aware swizzle: blockIdx % 8 = XCD (round-robin dispatch).
    // Pin each XCD to one batch b (2 XCDs per batch) so the 4.0 MiB per-batch
    // fm slice stays resident in that XCD's 4 MiB L2.
    const int xcd  = blockIdx.x & 7;        // 0..7
    const int slot = blockIdx.x >> 3;       // 0..783
    const int b    = xcd >> 1;              // 0..3
    const int half = xcd & 1;               // 0..1
    const int cell_in_b = (half * BLOCKS_PER_HALF + slot) * 4 + wave;  // 0..6271

    // decode (r, q, p) with p FASTEST: consecutive waves take adjacent w-bins
    // of the SAME h-bin rows -> contiguous ~12 KB sweeps per fm row instead of
    // scattered 3 KB islands (L2 sector + DRAM row locality).
    const int p = cell_in_b % PW;
    int t = cell_in_b / PW;
    const int q = t % PH;
    const int r = t / PH;

    // Scalarize the ROI fetch: index is wave-uniform -> s_load path.
    const int ridx = __builtin_amdgcn_readfirstlane(b * R + r);
    const float* roi = rois + (size_t)ridx * 4;
    const float x1 = roi[0], y1 = roi[1], x2 = roi[2], y2 = roi[3];

    // jnp.round = round-half-to-even -> rintf under default RN mode
    int ws = max((int)rintf(x1), 0);
    int hs = max((int)rintf(y1), 0);
    int we = min((int)rintf(x2), W);
    int he = min((int)rintf(y2), H);

    // TF reshape quirk: out[b,r,p,q,:] = max over h-bin q, w-bin p.
    // Replicate exact fp32 arithmetic of the reference.
    const float hstep = (float)(he - hs) / 7.0f;
    const float wstep = (float)(we - ws) / 7.0f;
    const int hlo = hs + (int)((float)q * hstep);
    const int hhi = (q < PH - 1) ? (hs + (int)((float)(q + 1) * hstep)) : he;
    const int wlo = ws + (int)((float)p * wstep);
    const int whi = (p < PW - 1) ? (ws + (int)((float)(p + 1) * wstep)) : we;

    const int nw = whi - wlo;              // >= 1 (no empty bins by construction)
    const int nh = hhi - hlo;
    const int n  = nh * nw;                // total (h,w) visits, wave-uniform

    const float* gp = fm + ((size_t)(b * H + hlo) * W + wlo) * C + lane * 4;
    int gw = 0;
    const size_t rstep = (size_t)(W - nw + 1) * C;  // last elem of row -> first of next row

    f32x4 acc = { -INFINITY, -INFINITY, -INFINITY, -INFINITY };

#define LOADV(dst) (dst) = *(const f32x4*)gp
#define ADV() { if (++gw == nw) { gw = 0; gp += rstep; } else { gp += (size_t)C; } }
#define FM(vv) { acc.x = fmaxf(acc.x, (vv).x); acc.y = fmaxf(acc.y, (vv).y); \
                 acc.z = fmaxf(acc.z, (vv).z); acc.w = fmaxf(acc.w, (vv).w); }

    if (n >= 4) {
        // 4-deep rotating software pipeline, exactly n loads.
        f32x4 v0, v1, v2, v3;
        LOADV(v0); ADV(); LOADV(v1); ADV(); LOADV(v2); ADV(); LOADV(v3); ADV();
        int k = n - 4;
        while (k >= 4) {
            FM(v0); LOADV(v0); ADV();
            FM(v1); LOADV(v1); ADV();
            FM(v2); LOADV(v2); ADV();
            FM(v3); LOADV(v3); ADV();
            k -= 4;
        }
        // tail: k in [0,3]; fmax is commutative, every slot drains at the end.
        if (k > 0) { FM(v0); LOADV(v0); ADV(); }
        if (k > 1) { FM(v1); LOADV(v1); ADV(); }
        if (k > 2) { FM(v2); LOADV(v2); ADV(); }
        FM(v0); FM(v1); FM(v2); FM(v3);
    } else {
        for (int i = 0; i < n; ++i) {
            f32x4 v; LOADV(v); ADV(); FM(v);
        }
    }

    // Non-temporal store: out (25.7 MB) is write-once; keep it from evicting
    // the fm slice out of the per-XCD L2.
    const int cell = ((b * R + r) * PH + p) * PW + q;
    float* op = out + (size_t)cell * C + lane * 4;
    __builtin_nontemporal_store(acc, (f32x4*)op);
}

extern "C" void kernel_launch(void* const* d_in, const int* in_sizes, int n_in,
                              void* d_out, int out_size, void* d_ws, size_t ws_size,
                              hipStream_t stream) {
    const float* fm   = (const float*)d_in[0];
    const float* rois = (const float*)d_in[1];
    float* out = (float*)d_out;

    roi_pool_kernel<<<BLOCKS_TOTAL, 256, 0, stream>>>(fm, rois, out);
}